// Round 7
// baseline (146.848 us; speedup 1.0000x reference)
//
#include <hip/hip_runtime.h>
#include <math.h>

// SupCR loss, MI355X. Round 15 (row_kernel restructure):
//  - row_kernel: keys no longer staged in LDS -- binary searches probe slab[]
//    directly (8KB, shared by all blocks -> L1-resident); rows A+B fused into
//    ONE scan phase with PfA/SfA/PfB/SfB (32KB LDS, 4 blocks/CU); barriers
//    9 -> 4. Same math, same scan order, same fp32+CS bias.
//  - prep_sort / GEMM (128x64, 272 lower-band tiles) / finalize: r14 exact.

#define NN 2048      // N = B*V
#define BB 1024      // B
#define DD 512       // D
#define NT 256
#define NEGINF (-INFINITY)
#define CS 64.0f     // exponent pre-scale bias

typedef short s16x8 __attribute__((ext_vector_type(8)));
typedef float f32x4 __attribute__((ext_vector_type(4)));

// row i of the virtual cf matrix lives at F + ((i%B)*2 + i/B)*D
__device__ __forceinline__ const float* cf_row(const float* F, int i) {
    return F + ((size_t)(i & (BB - 1)) * 2 + (size_t)(i >> 10)) * DD;
}

__device__ __forceinline__ unsigned bf_rne(float x) {
    const unsigned u = __float_as_uint(x);
    return (u + 0x7FFFu + ((u >> 16) & 1u)) >> 16;
}
__device__ __forceinline__ float bf_val(unsigned h) {
    return __uint_as_float(h << 16);
}

// ---------------- kernel 0: fused prep (blocks 0..255) + rank sort (256,257) ----
__global__ __launch_bounds__(512) void prep_sort_kernel(const float* __restrict__ F,
                                                        const float* __restrict__ labels,
                                                        ushort* __restrict__ Ahi,
                                                        ushort* __restrict__ Alo,
                                                        float* __restrict__ sq,
                                                        float* __restrict__ slab,
                                                        int* __restrict__ sj) {
    __shared__ float lab[BB];
    const int blk = blockIdx.x;
    const int t = threadIdx.x;

    if (blk < 256) {
        // ---- prep: 8 rows per block, one row per wave ----
        const int lane = t & 63;
        const int w = t >> 6;
        const int i = blk * 8 + w;
        const float* src = cf_row(F, i);
        const float4 v0 = reinterpret_cast<const float4*>(src)[lane];
        const float4 v1 = reinterpret_cast<const float4*>(src)[lane + 64];
        float ss = v0.x * v0.x + v0.y * v0.y + v0.z * v0.z + v0.w * v0.w
                 + v1.x * v1.x + v1.y * v1.y + v1.z * v1.z + v1.w * v1.w;
        #pragma unroll
        for (int st = 32; st > 0; st >>= 1) ss += __shfl_down(ss, st);
        if (lane == 0) sq[i] = ss;

        const float a[8] = {v0.x, v0.y, v0.z, v0.w, v1.x, v1.y, v1.z, v1.w};
        ushort h[8], l[8];
        #pragma unroll
        for (int e = 0; e < 8; ++e) {
            const unsigned hb = bf_rne(a[e]);
            h[e] = (ushort)hb;
            l[e] = (ushort)bf_rne(a[e] - bf_val(hb));
        }
        const size_t base = (size_t)i * DD;
        *reinterpret_cast<ushort4*>(&Ahi[base + lane * 4])       = make_ushort4(h[0], h[1], h[2], h[3]);
        *reinterpret_cast<ushort4*>(&Ahi[base + 256 + lane * 4]) = make_ushort4(h[4], h[5], h[6], h[7]);
        *reinterpret_cast<ushort4*>(&Alo[base + lane * 4])       = make_ushort4(l[0], l[1], l[2], l[3]);
        *reinterpret_cast<ushort4*>(&Alo[base + 256 + lane * 4]) = make_ushort4(l[4], l[5], l[6], l[7]);
    } else {
        // ---- rank sort: block 256 -> elements 0..511, block 257 -> 512..1023 ----
        lab[t] = labels[t];
        lab[t + 512] = labels[t + 512];
        __syncthreads();
        const int e = (blk - 256) * 512 + t;
        const float li = lab[e];
        int rank = 0;
        const float4* l4 = reinterpret_cast<const float4*>(lab);
        #pragma unroll 4
        for (int j = 0; j < BB / 4; ++j) {
            const float4 v = l4[j];
            const int j0 = j * 4;
            rank += (v.x < li) || (v.x == li && (j0 + 0) < e);
            rank += (v.y < li) || (v.y == li && (j0 + 1) < e);
            rank += (v.z < li) || (v.z == li && (j0 + 2) < e);
            rank += (v.w < li) || (v.w == li && (j0 + 3) < e);
        }
        slab[2 * rank]     = li;
        slab[2 * rank + 1] = li;
        sj[2 * rank]     = e;
        sj[2 * rank + 1] = e + BB;
    }
}

// ---------------- kernel 1: MFMA dist, symmetric (lower tiles only) ---------
#define TM 128
#define TN 64
#define TK 32
__global__ __launch_bounds__(256) void gemm_dist_kernel(const ushort* __restrict__ Ahi,
                                                        const ushort* __restrict__ Alo,
                                                        const float* __restrict__ sq,
                                                        const int* __restrict__ sj,
                                                        float* __restrict__ distp) {
    __shared__ ushort Ah[4][TM][8];
    __shared__ ushort Al[4][TM][8];
    __shared__ ushort Bh[4][TN][8];
    __shared__ ushort Bl[4][TN][8];
    __shared__ int   sjcA[TM];
    __shared__ int   sjcB[TN];
    __shared__ float sqA[TM];
    __shared__ float sqB[TN];

    const int t = threadIdx.x;
    const int lane = t & 63;
    const int w = t >> 6;

    // tile id -> (by, bx) over the lower-triangular band: C(by)=by*(by+1)
    const int id = blockIdx.x;
    int by = (int)((__fsqrt_rn(4.0f * (float)id + 1.0f) - 1.0f) * 0.5f);
    while ((by + 1) * (by + 2) <= id) ++by;
    while (by * (by + 1) > id) --by;
    const int bx = id - by * (by + 1);          // 0 .. 2*by+1
    const int row0 = by * TM;
    const int col0 = bx * TN;
    const bool below = (bx < 2 * by);           // strictly left of diag square

    if (t < TM) {
        const int s = sj[row0 + t];
        sjcA[t] = s; sqA[t] = sq[s];
    } else if (t < TM + TN) {
        const int u = t - TM;
        const int s = sj[col0 + u];
        sjcB[u] = s; sqB[u] = sq[s];
    }
    __syncthreads();
    const int rr = t >> 2;
    const int cq = t & 3;
    const size_t gA0 = (size_t)sjcA[rr] * DD + cq * 8;
    const size_t gA1 = (size_t)sjcA[64 + rr] * DD + cq * 8;
    const size_t gB0 = (size_t)sjcB[rr] * DD + cq * 8;

    f32x4 acc[2][4] = {};
    const int m = lane & 15;
    const int q = lane >> 4;

    for (int kt = 0; kt < DD / TK; ++kt) {
        __syncthreads();
        const size_t ko = (size_t)kt * TK;
        *reinterpret_cast<int4*>(&Ah[cq][rr][0])      = *reinterpret_cast<const int4*>(&Ahi[gA0 + ko]);
        *reinterpret_cast<int4*>(&Al[cq][rr][0])      = *reinterpret_cast<const int4*>(&Alo[gA0 + ko]);
        *reinterpret_cast<int4*>(&Ah[cq][64 + rr][0]) = *reinterpret_cast<const int4*>(&Ahi[gA1 + ko]);
        *reinterpret_cast<int4*>(&Al[cq][64 + rr][0]) = *reinterpret_cast<const int4*>(&Alo[gA1 + ko]);
        *reinterpret_cast<int4*>(&Bh[cq][rr][0])      = *reinterpret_cast<const int4*>(&Ahi[gB0 + ko]);
        *reinterpret_cast<int4*>(&Bl[cq][rr][0])      = *reinterpret_cast<const int4*>(&Alo[gB0 + ko]);
        __syncthreads();

        s16x8 fah[2], fal[2], fbh[4], fbl[4];
        #pragma unroll
        for (int mt = 0; mt < 2; ++mt) {
            fah[mt] = *reinterpret_cast<const s16x8*>(&Ah[q][w * 32 + mt * 16 + m][0]);
            fal[mt] = *reinterpret_cast<const s16x8*>(&Al[q][w * 32 + mt * 16 + m][0]);
        }
        #pragma unroll
        for (int nt = 0; nt < 4; ++nt) {
            fbh[nt] = *reinterpret_cast<const s16x8*>(&Bh[q][nt * 16 + m][0]);
            fbl[nt] = *reinterpret_cast<const s16x8*>(&Bl[q][nt * 16 + m][0]);
        }
        #pragma unroll
        for (int mt = 0; mt < 2; ++mt)
            #pragma unroll
            for (int nt = 0; nt < 4; ++nt) {
                acc[mt][nt] = __builtin_amdgcn_mfma_f32_16x16x32_bf16(fah[mt], fbh[nt], acc[mt][nt], 0, 0, 0);
                acc[mt][nt] = __builtin_amdgcn_mfma_f32_16x16x32_bf16(fah[mt], fbl[nt], acc[mt][nt], 0, 0, 0);
                acc[mt][nt] = __builtin_amdgcn_mfma_f32_16x16x32_bf16(fal[mt], fbh[nt], acc[mt][nt], 0, 0, 0);
            }
    }

    #pragma unroll
    for (int mt = 0; mt < 2; ++mt) {
        const int lr0 = w * 32 + mt * 16 + q * 4;
        #pragma unroll
        for (int nt = 0; nt < 4; ++nt) {
            const int lc = nt * 16 + m;
            float o[4];
            #pragma unroll
            for (int r = 0; r < 4; ++r) {
                const float d2 = sqA[lr0 + r] + sqB[lc] - 2.0f * acc[mt][nt][r];
                o[r] = (d2 > 0.f) ? sqrtf(d2) : 0.f;
            }
            #pragma unroll
            for (int r = 0; r < 4; ++r)
                distp[(size_t)(row0 + lr0 + r) * NN + col0 + lc] = o[r];
            if (below) {
                const float4 o4 = make_float4(o[0], o[1], o[2], o[3]);
                *reinterpret_cast<float4*>(&distp[(size_t)(col0 + lc) * NN + row0 + lr0]) = o4;
            }
        }
    }
}

// ---------------- kernel 2: row-pair, fused scans, slab-probing searches ----
// first idx in [lo,hi) with |slab[idx]-x| >= d (right segment: non-decreasing)
__device__ __forceinline__ int bs_right_g(const float* __restrict__ slab, float x,
                                          float d, int lo, int hi) {
    while (lo < hi) {
        const int mid = (lo + hi) >> 1;
        if (fabsf(slab[mid] - x) >= d) hi = mid; else lo = mid + 1;
    }
    return lo;
}
// first idx in [lo,hi) with |slab[idx]-x| < d (left segment: non-increasing)
__device__ __forceinline__ int bs_left_g(const float* __restrict__ slab, float x,
                                         float d, int lo, int hi) {
    while (lo < hi) {
        const int mid = (lo + hi) >> 1;
        if (fabsf(slab[mid] - x) < d) hi = mid; else lo = mid + 1;
    }
    return lo;
}

__global__ __launch_bounds__(256) void row_kernel(const float* __restrict__ distp,
                                                  const float* __restrict__ slab,
                                                  double* __restrict__ rowval) {
    __shared__ float PfA[NN];
    __shared__ float SfA[NN];
    __shared__ float PfB[NN];
    __shared__ float SfB[NN];
    __shared__ float wmxA[4], wmxB[4], wpsA[4], wssA[4], wpsB[4], wssB[4];
    __shared__ double wDA[4], wLA[4], wDB[4], wLB[4];

    const int pr = blockIdx.x;           // pair index
    const int rA = 2 * pr, rB = 2 * pr + 1;
    const int t = threadIdx.x;
    const int lane = t & 63;
    const int w = t >> 6;
    const float x = slab[rA];
    const float negInvT = -1.0f / 0.07f;
    const float* drowA = &distp[(size_t)rA * NN];
    const float* drowB = &distp[(size_t)rB * NN];
    const int cb = t * 8;

    // ---- vals for both rows, row maxima, distance sums ----
    float vA[8], vB[8];
    double dsumA = 0.0, dsumB = 0.0;
    float mxA = NEGINF, mxB = NEGINF;
    #pragma unroll
    for (int e = 0; e < 2; ++e) {
        const float4 a4 = reinterpret_cast<const float4*>(drowA)[2 * t + e];
        const float4 b4 = reinterpret_cast<const float4*>(drowB)[2 * t + e];
        const float av[4] = {a4.x, a4.y, a4.z, a4.w};
        const float bv[4] = {b4.x, b4.y, b4.z, b4.w};
        #pragma unroll
        for (int c = 0; c < 4; ++c) {
            const int pc = cb + e * 4 + c;
            if (pc == rA) vA[e * 4 + c] = NEGINF;
            else { const float vv = av[c] * negInvT; vA[e * 4 + c] = vv; mxA = fmaxf(mxA, vv); dsumA += (double)av[c]; }
            if (pc == rB) vB[e * 4 + c] = NEGINF;
            else { const float vv = bv[c] * negInvT; vB[e * 4 + c] = vv; mxB = fmaxf(mxB, vv); dsumB += (double)bv[c]; }
        }
    }
    #pragma unroll
    for (int st = 32; st > 0; st >>= 1) {
        mxA = fmaxf(mxA, __shfl_down(mxA, st));
        mxB = fmaxf(mxB, __shfl_down(mxB, st));
    }
    if (lane == 0) { wmxA[w] = mxA; wmxB[w] = mxB; }

    // ---- window boundaries (key-determined, shared by both rows) ----
    // keys probed directly from slab (L1-resident, shared by all blocks)
    int L8[8], R8[8];
    float d8[8];
    {
        const float4 s0 = reinterpret_cast<const float4*>(slab)[2 * t];
        const float4 s1 = reinterpret_cast<const float4*>(slab)[2 * t + 1];
        d8[0] = fabsf(s0.x - x); d8[1] = fabsf(s0.y - x);
        d8[2] = fabsf(s0.z - x); d8[3] = fabsf(s0.w - x);
        d8[4] = fabsf(s1.x - x); d8[5] = fabsf(s1.y - x);
        d8[6] = fabsf(s1.z - x); d8[7] = fabsf(s1.w - x);
    }
    const int a = cb, b = cb + 7;
    {
        const int le = (rA - 1 < b) ? rA - 1 : b;
        if (a <= le) {
            const float da = d8[0];
            const int Ra = bs_right_g(slab, x, da, rA, NN);
            int Rl = Ra;
            if (le > a) Rl = bs_right_g(slab, x, d8[le - a], rA, Ra);
            for (int p = a; p <= le; ++p) {
                const float d = d8[p - a];
                int R;
                if (p == a) R = Ra;
                else if (p == le) R = Rl;
                else R = bs_right_g(slab, x, d, Rl, Ra);
                int L = p + 1;
                while (L < rA && fabsf(slab[L] - x) == d) ++L;
                L8[p - a] = L; R8[p - a] = R;
            }
        }
        const int rs = (rA + 1 > a) ? rA + 1 : a;
        if (rs <= b) {
            const float dr = d8[rs - a];
            const int Lr = bs_left_g(slab, x, dr, 0, rA);
            int Lb = Lr;
            if (b > rs) Lb = bs_left_g(slab, x, d8[b - a], 0, Lr);
            for (int p = rs; p <= b; ++p) {
                const float d = d8[p - a];
                int L;
                if (p == rs) L = Lr;
                else if (p == b) L = Lb;
                else L = bs_left_g(slab, x, d, Lb, Lr);
                int R = p;
                while (R > rA && fabsf(slab[R - 1] - x) == d) --R;
                L8[p - a] = L; R8[p - a] = R;
            }
        }
        if (rA >= a && rA <= b) { L8[rA - a] = rA; R8[rA - a] = rA; }
    }

    __syncthreads();   // B1: wave maxima ready
    const float MA = fmaxf(fmaxf(wmxA[0], wmxA[1]), fmaxf(wmxA[2], wmxA[3]));
    const float MB = fmaxf(fmaxf(wmxB[0], wmxB[1]), fmaxf(wmxB[2], wmxB[3]));

    // ---- fused scans: prefix+suffix for BOTH rows, 2 barriers total ----
    float exA[8], sxA[8], exB[8], sxB[8];
    float xofsPA, xofsSA, xofsPB, xofsSB;
    {
        float e8A[8], e8B[8];
        #pragma unroll
        for (int jj = 0; jj < 8; ++jj) {
            e8A[jj] = __expf(vA[jj] - MA + CS);
            e8B[jj] = __expf(vB[jj] - MB + CS);
        }
        float runPA = 0.f, runPB = 0.f;
        #pragma unroll
        for (int jj = 0; jj < 8; ++jj) {
            exA[jj] = runPA; runPA += e8A[jj];
            exB[jj] = runPB; runPB += e8B[jj];
        }
        float runSA = 0.f, runSB = 0.f;
        #pragma unroll
        for (int jj = 7; jj >= 0; --jj) {
            runSA += e8A[jj]; sxA[jj] = runSA;
            runSB += e8B[jj]; sxB[jj] = runSB;
        }
        float incPA = runPA, incPB = runPB, incSA = runSA, incSB = runSB;
        #pragma unroll
        for (int st = 1; st < 64; st <<= 1) {
            const float nPA = __shfl_up(incPA, st);
            const float nPB = __shfl_up(incPB, st);
            const float nSA = __shfl_down(incSA, st);
            const float nSB = __shfl_down(incSB, st);
            if (lane >= st)      { incPA += nPA; incPB += nPB; }
            if (lane + st < 64)  { incSA += nSA; incSB += nSB; }
        }
        xofsPA = __shfl_up(incPA, 1);
        xofsPB = __shfl_up(incPB, 1);
        xofsSA = __shfl_down(incSA, 1);
        xofsSB = __shfl_down(incSB, 1);
        if (lane == 0)  { xofsPA = 0.f; xofsPB = 0.f; wssA[w] = incSA; wssB[w] = incSB; }
        if (lane == 63) { xofsSA = 0.f; xofsSB = 0.f; wpsA[w] = incPA; wpsB[w] = incPB; }
    }
    __syncthreads();   // B2: wave scan partials ready
    #pragma unroll
    for (int ww = 0; ww < 3; ++ww)
        if (ww < w) { xofsPA += wpsA[ww]; xofsPB += wpsB[ww]; }
    #pragma unroll
    for (int ww = 1; ww < 4; ++ww)
        if (ww > w) { xofsSA += wssA[ww]; xofsSB += wssB[ww]; }
    #pragma unroll
    for (int jj = 0; jj < 8; ++jj) {
        PfA[cb + jj] = exA[jj] + xofsPA;
        SfA[cb + jj] = sxA[jj] + xofsSA;
        PfB[cb + jj] = exB[jj] + xofsPB;
        SfB[cb + jj] = sxB[jj] + xofsSB;
    }
    __syncthreads();   // B3: all four arrays ready

    // ---- window lookups for both rows ----
    double lnsumA = 0.0, lnsumB = 0.0;
    const float MBA = MA - CS;
    const float MBB = MB - CS;
    #pragma unroll
    for (int jj = 0; jj < 8; ++jj) {
        const int p = cb + jj;
        const int L = L8[jj], R = R8[jj];
        if (p != rA) {
            const float sfa = (R < NN) ? SfA[R] : 0.f;
            const float s = fmaxf(PfA[L] + sfa, 1e-38f);
            lnsumA += (double)(MBA + __logf(s));
        }
        if (p != rB) {
            const float sfb = (R < NN) ? SfB[R] : 0.f;
            const float s = fmaxf(PfB[L] + sfb, 1e-38f);
            lnsumB += (double)(MBB + __logf(s));
        }
    }

    // ---- reductions (both rows) ----
    #pragma unroll
    for (int st = 32; st > 0; st >>= 1) {
        dsumA  += __shfl_down(dsumA, st);
        lnsumA += __shfl_down(lnsumA, st);
        dsumB  += __shfl_down(dsumB, st);
        lnsumB += __shfl_down(lnsumB, st);
    }
    if (lane == 0) { wDA[w] = dsumA; wLA[w] = lnsumA; wDB[w] = dsumB; wLB[w] = lnsumB; }
    __syncthreads();   // B4
    if (t == 0) {
        rowval[rA] = (-(wDA[0] + wDA[1] + wDA[2] + wDA[3]) / 0.07)
                   - (wLA[0] + wLA[1] + wLA[2] + wLA[3]);
        rowval[rB] = (-(wDB[0] + wDB[1] + wDB[2] + wDB[3]) / 0.07)
                   - (wLB[0] + wLB[1] + wLB[2] + wLB[3]);
    }
}

// ---------------- kernel 3: final mean ----------------
__global__ __launch_bounds__(256) void finalize_kernel(const double* __restrict__ rowval,
                                                       float* __restrict__ out) {
    __shared__ double red[NT];
    const int t = threadIdx.x;
    double s = 0.0;
    for (int j = t; j < NN; j += NT) s += rowval[j];
    red[t] = s;
    __syncthreads();
    for (int ofs = NT / 2; ofs > 0; ofs >>= 1) {
        if (t < ofs) red[t] += red[t + ofs];
        __syncthreads();
    }
    if (t == 0) {
        out[0] = (float)(-red[0] / ((double)NN * (double)(NN - 1)));
    }
}

extern "C" void kernel_launch(void* const* d_in, const int* in_sizes, int n_in,
                              void* d_out, int out_size, void* d_ws, size_t ws_size,
                              hipStream_t stream) {
    const float* features = (const float*)d_in[0];  // [1024, 2, 512] fp32
    const float* labels   = (const float*)d_in[1];  // [1024] fp32
    float* out = (float*)d_out;

    char* ws = (char*)d_ws;
    size_t off = 0;
    float*  sq     = (float*) (ws + off); off += NN * sizeof(float);
    float*  slab   = (float*) (ws + off); off += NN * sizeof(float);
    int*    sj     = (int*)   (ws + off); off += NN * sizeof(int);
    double* rowval = (double*)(ws + off); off += NN * sizeof(double);
    ushort* Ahi    = (ushort*)(ws + off); off += (size_t)NN * DD * sizeof(ushort);
    ushort* Alo    = (ushort*)(ws + off); off += (size_t)NN * DD * sizeof(ushort);
    float*  distp  = (float*) (ws + off); off += (size_t)NN * NN * sizeof(float);

    prep_sort_kernel<<<258, 512, 0, stream>>>(features, labels, Ahi, Alo, sq, slab, sj);
    gemm_dist_kernel<<<16 * 17, NT, 0, stream>>>(Ahi, Alo, sq, sj, distp);  // 272 lower tiles
    row_kernel<<<NN / 2, NT, 0, stream>>>(distp, slab, rowval);
    finalize_kernel<<<1, NT, 0, stream>>>(rowval, out);
}